// Round 1
// baseline (419.408 us; speedup 1.0000x reference)
//
#include <hip/hip_runtime.h>

// Problem constants (match reference setup_inputs()).
#define NUM_ENTITIES 100000
#define NUM_RELATIONS 256

// out[col % E] += p_scores[mask] * e_scores[row]  for each edge.
__global__ __launch_bounds__(256) void mp_scatter_kernel(
    const int* __restrict__ row,     // [nnz]
    const int* __restrict__ col,     // [nnz]
    const int* __restrict__ mask,    // [nnz]
    const float* __restrict__ e,     // [E]
    const float* __restrict__ p,     // [R]
    float* __restrict__ out,         // [E]
    int nnz)
{
    __shared__ float p_lds[NUM_RELATIONS];
    if (threadIdx.x < NUM_RELATIONS) p_lds[threadIdx.x] = p[threadIdx.x];
    __syncthreads();

    const int tid    = blockIdx.x * blockDim.x + threadIdx.x;
    const int stride = gridDim.x * blockDim.x;
    const int nvec   = nnz >> 2;  // nnz divisible by 4 (8,000,000)

    const int4* __restrict__ row4  = reinterpret_cast<const int4*>(row);
    const int4* __restrict__ col4  = reinterpret_cast<const int4*>(col);
    const int4* __restrict__ mask4 = reinterpret_cast<const int4*>(mask);

    for (int v = tid; v < nvec; v += stride) {
        int4 r4 = row4[v];
        int4 c4 = col4[v];
        int4 m4 = mask4[v];

        float v0 = p_lds[m4.x] * e[r4.x];
        float v1 = p_lds[m4.y] * e[r4.y];
        float v2 = p_lds[m4.z] * e[r4.z];
        float v3 = p_lds[m4.w] * e[r4.w];

        atomicAdd(&out[(unsigned)c4.x % NUM_ENTITIES], v0);
        atomicAdd(&out[(unsigned)c4.y % NUM_ENTITIES], v1);
        atomicAdd(&out[(unsigned)c4.z % NUM_ENTITIES], v2);
        atomicAdd(&out[(unsigned)c4.w % NUM_ENTITIES], v3);
    }
}

extern "C" void kernel_launch(void* const* d_in, const int* in_sizes, int n_in,
                              void* d_out, int out_size, void* d_ws, size_t ws_size,
                              hipStream_t stream) {
    // Input order per setup_inputs(): indices [2, nnz], e_scores [E,1],
    // p_scores [R,1], relation_mask [nnz].
    const int*   indices = (const int*)d_in[0];
    const float* e       = (const float*)d_in[1];
    const float* p       = (const float*)d_in[2];
    const int*   mask    = (const int*)d_in[3];

    const int nnz = in_sizes[3];            // 8,000,000
    const int* row = indices;               // indices[0, :]
    const int* col = indices + nnz;         // indices[1, :]

    float* out = (float*)d_out;

    // Output is poisoned once before timing and never re-poisoned; we must
    // zero it ourselves every call (accumulation target).
    hipMemsetAsync(out, 0, (size_t)out_size * sizeof(float), stream);

    const int block = 256;
    const int grid  = 2048;  // grid-stride; ~4 vec-iterations per thread
    mp_scatter_kernel<<<grid, block, 0, stream>>>(row, col, mask, e, p, out, nnz);
}

// Round 2
// 403.227 us; speedup vs baseline: 1.0401x; 1.0401x over previous
//
#include <hip/hip_runtime.h>

// Problem constants (match reference setup_inputs()).
#define NUM_ENTITIES 100000
#define NUM_RELATIONS 256
#define NUM_XCD 8

// Phase 1: out_ws[xcd][col % E] += p[mask] * e[row] for each edge.
// Atomics are workgroup-scope -> executed in the issuing XCD's L2 (no
// cross-XCD write-through). Each XCD only ever touches its own copy, so
// L2-local atomicity is sufficient for correctness.
__global__ __launch_bounds__(256) void mp_scatter_xcd_kernel(
    const int* __restrict__ row,     // [nnz]
    const int* __restrict__ col,     // [nnz]
    const int* __restrict__ mask,    // [nnz]
    const float* __restrict__ e,     // [E]
    const float* __restrict__ p,     // [R]
    float* __restrict__ ws,          // [NUM_XCD * E] zeroed partials
    int nnz)
{
    __shared__ float p_lds[NUM_RELATIONS];
    if (threadIdx.x < NUM_RELATIONS) p_lds[threadIdx.x] = p[threadIdx.x];
    __syncthreads();

    // Wave-uniform XCD id (0..7 on MI355X).
    unsigned xid;
    asm volatile("s_getreg_b32 %0, hwreg(HW_REG_XCC_ID)" : "=s"(xid));
    float* __restrict__ myout = ws + (size_t)(xid & (NUM_XCD - 1)) * NUM_ENTITIES;

    const int tid    = blockIdx.x * blockDim.x + threadIdx.x;
    const int stride = gridDim.x * blockDim.x;
    const int nvec   = nnz >> 2;  // nnz divisible by 4 (8,000,000)

    const int4* __restrict__ row4  = reinterpret_cast<const int4*>(row);
    const int4* __restrict__ col4  = reinterpret_cast<const int4*>(col);
    const int4* __restrict__ mask4 = reinterpret_cast<const int4*>(mask);

    for (int v = tid; v < nvec; v += stride) {
        int4 r4 = row4[v];
        int4 c4 = col4[v];
        int4 m4 = mask4[v];

        float v0 = p_lds[m4.x] * e[r4.x];
        float v1 = p_lds[m4.y] * e[r4.y];
        float v2 = p_lds[m4.z] * e[r4.z];
        float v3 = p_lds[m4.w] * e[r4.w];

        __hip_atomic_fetch_add(&myout[(unsigned)c4.x % NUM_ENTITIES], v0,
                               __ATOMIC_RELAXED, __HIP_MEMORY_SCOPE_WORKGROUP);
        __hip_atomic_fetch_add(&myout[(unsigned)c4.y % NUM_ENTITIES], v1,
                               __ATOMIC_RELAXED, __HIP_MEMORY_SCOPE_WORKGROUP);
        __hip_atomic_fetch_add(&myout[(unsigned)c4.z % NUM_ENTITIES], v2,
                               __ATOMIC_RELAXED, __HIP_MEMORY_SCOPE_WORKGROUP);
        __hip_atomic_fetch_add(&myout[(unsigned)c4.w % NUM_ENTITIES], v3,
                               __ATOMIC_RELAXED, __HIP_MEMORY_SCOPE_WORKGROUP);
    }
}

// Phase 2: out[i] = sum over the 8 XCD partials. float4-vectorized
// (E = 100000 is divisible by 4; each copy stride is 16B-aligned).
__global__ __launch_bounds__(256) void mp_reduce_kernel(
    const float* __restrict__ ws,    // [NUM_XCD * E]
    float* __restrict__ out)         // [E]
{
    const int nv = NUM_ENTITIES / 4;
    int i = blockIdx.x * blockDim.x + threadIdx.x;
    if (i >= nv) return;
    const float4* __restrict__ ws4 = reinterpret_cast<const float4*>(ws);
    float4 s = ws4[i];
    #pragma unroll
    for (int x = 1; x < NUM_XCD; ++x) {
        float4 t = ws4[(size_t)x * nv + i];
        s.x += t.x; s.y += t.y; s.z += t.z; s.w += t.w;
    }
    reinterpret_cast<float4*>(out)[i] = s;
}

// Fallback (only if ws is unexpectedly small): direct device-scope atomics.
__global__ __launch_bounds__(256) void mp_scatter_direct_kernel(
    const int* __restrict__ row, const int* __restrict__ col,
    const int* __restrict__ mask, const float* __restrict__ e,
    const float* __restrict__ p, float* __restrict__ out, int nnz)
{
    __shared__ float p_lds[NUM_RELATIONS];
    if (threadIdx.x < NUM_RELATIONS) p_lds[threadIdx.x] = p[threadIdx.x];
    __syncthreads();
    const int tid    = blockIdx.x * blockDim.x + threadIdx.x;
    const int stride = gridDim.x * blockDim.x;
    for (int i = tid; i < nnz; i += stride) {
        float v = p_lds[mask[i]] * e[row[i]];
        atomicAdd(&out[(unsigned)col[i] % NUM_ENTITIES], v);
    }
}

extern "C" void kernel_launch(void* const* d_in, const int* in_sizes, int n_in,
                              void* d_out, int out_size, void* d_ws, size_t ws_size,
                              hipStream_t stream) {
    const int*   indices = (const int*)d_in[0];
    const float* e       = (const float*)d_in[1];
    const float* p       = (const float*)d_in[2];
    const int*   mask    = (const int*)d_in[3];

    const int nnz = in_sizes[3];            // 8,000,000
    const int* row = indices;               // indices[0, :]
    const int* col = indices + nnz;         // indices[1, :]
    float* out = (float*)d_out;

    const size_t ws_needed = (size_t)NUM_XCD * NUM_ENTITIES * sizeof(float);
    if (ws_size < ws_needed) {
        // Safety fallback: previous round's correct (slower) path.
        hipMemsetAsync(out, 0, (size_t)out_size * sizeof(float), stream);
        mp_scatter_direct_kernel<<<2048, 256, 0, stream>>>(row, col, mask, e, p, out, nnz);
        return;
    }

    float* ws = (float*)d_ws;
    hipMemsetAsync(ws, 0, ws_needed, stream);

    mp_scatter_xcd_kernel<<<2048, 256, 0, stream>>>(row, col, mask, e, p, ws, nnz);

    const int nv = NUM_ENTITIES / 4;            // 25000
    mp_reduce_kernel<<<(nv + 255) / 256, 256, 0, stream>>>(ws, out);
}

// Round 3
// 97.714 us; speedup vs baseline: 4.2922x; 4.1266x over previous
//
#include <hip/hip_runtime.h>

// Problem constants (match reference setup_inputs()).
#define NUM_ENTITIES 100000
#define NUM_RELATIONS 256

// Range-partitioned LDS privatization.
#define RANGES 4
#define RSIZE (NUM_ENTITIES / RANGES)   // 25000 floats = 100000 B LDS
#define CHUNKS 64
#define BLOCK 512

// Phase 1: each block owns (range r, edge-chunk c). It scans chunk c of the
// edge list and accumulates edges with seg in [r*RSIZE, (r+1)*RSIZE) into an
// LDS accumulator via LDS atomics (ds_add_f32 — per-CU, no memory-side
// traffic). The full partial is then flushed to a private ws slot.
__global__ __launch_bounds__(BLOCK) void mp_range_kernel(
    const int* __restrict__ row,     // [nnz]
    const int* __restrict__ col,     // [nnz]
    const int* __restrict__ mask,    // [nnz]
    const float* __restrict__ e,     // [E]
    const float* __restrict__ p,     // [R]
    float* __restrict__ ws,          // [RANGES * CHUNKS * RSIZE]
    int nnz)
{
    __shared__ float acc[RSIZE];
    __shared__ float p_lds[NUM_RELATIONS];

    if (threadIdx.x < NUM_RELATIONS) p_lds[threadIdx.x] = p[threadIdx.x];
    {   // zero LDS accumulator (vectorized)
        float4* a4 = reinterpret_cast<float4*>(acc);
        const float4 z = {0.f, 0.f, 0.f, 0.f};
        for (int i = threadIdx.x; i < RSIZE / 4; i += BLOCK) a4[i] = z;
    }
    __syncthreads();

    const int range = blockIdx.x & (RANGES - 1);
    const int chunk = blockIdx.x >> 2;
    const int base  = range * RSIZE;

    const int nvec      = nnz >> 2;
    const int per_chunk = (nvec + CHUNKS - 1) / CHUNKS;
    const int v_lo      = chunk * per_chunk;
    const int v_hi      = min(v_lo + per_chunk, nvec);

    const int4* __restrict__ row4  = reinterpret_cast<const int4*>(row);
    const int4* __restrict__ col4  = reinterpret_cast<const int4*>(col);
    const int4* __restrict__ mask4 = reinterpret_cast<const int4*>(mask);

    for (int v = v_lo + (int)threadIdx.x; v < v_hi; v += BLOCK) {
        int4 c4 = col4[v];
        int4 r4 = row4[v];
        int4 m4 = mask4[v];

        int o0 = (int)((unsigned)c4.x % NUM_ENTITIES) - base;
        int o1 = (int)((unsigned)c4.y % NUM_ENTITIES) - base;
        int o2 = (int)((unsigned)c4.z % NUM_ENTITIES) - base;
        int o3 = (int)((unsigned)c4.w % NUM_ENTITIES) - base;

        if ((unsigned)o0 < RSIZE) atomicAdd(&acc[o0], p_lds[m4.x] * e[r4.x]);
        if ((unsigned)o1 < RSIZE) atomicAdd(&acc[o1], p_lds[m4.y] * e[r4.y]);
        if ((unsigned)o2 < RSIZE) atomicAdd(&acc[o2], p_lds[m4.z] * e[r4.z]);
        if ((unsigned)o3 < RSIZE) atomicAdd(&acc[o3], p_lds[m4.w] * e[r4.w]);
    }

    // Scalar tail (nnz not divisible by 4) — handled once per range.
    if (chunk == 0) {
        for (int i = (nvec << 2) + (int)threadIdx.x; i < nnz; i += BLOCK) {
            int o = (int)((unsigned)col[i] % NUM_ENTITIES) - base;
            if ((unsigned)o < RSIZE) atomicAdd(&acc[o], p_lds[mask[i]] * e[row[i]]);
        }
    }

    __syncthreads();

    // Flush full partial (writes everything -> ws needs no pre-zeroing).
    float4* __restrict__ dst =
        reinterpret_cast<float4*>(ws + ((size_t)range * CHUNKS + chunk) * RSIZE);
    const float4* a4 = reinterpret_cast<const float4*>(acc);
    for (int i = threadIdx.x; i < RSIZE / 4; i += BLOCK) dst[i] = a4[i];
}

// Phase 2: out[r*RSIZE + o] = sum over chunks c of ws[(r*CHUNKS + c)*RSIZE + o].
// One thread per float4 of output (RSIZE % 4 == 0, so ranges stay aligned).
__global__ __launch_bounds__(256) void mp_reduce_kernel(
    const float* __restrict__ ws,
    float* __restrict__ out)
{
    const int nv4_per_range = RSIZE / 4;              // 6250
    const int nv4_total     = nv4_per_range * RANGES; // 25000
    int i = blockIdx.x * blockDim.x + threadIdx.x;
    if (i >= nv4_total) return;
    int r  = i / nv4_per_range;
    int ov = i - r * nv4_per_range;

    const float4* __restrict__ ws4 = reinterpret_cast<const float4*>(ws);
    size_t rbase = (size_t)r * CHUNKS * nv4_per_range;
    float4 s = ws4[rbase + ov];
    #pragma unroll 8
    for (int c = 1; c < CHUNKS; ++c) {
        float4 t = ws4[rbase + (size_t)c * nv4_per_range + ov];
        s.x += t.x; s.y += t.y; s.z += t.z; s.w += t.w;
    }
    reinterpret_cast<float4*>(out)[i] = s;
}

// Fallback (ws unexpectedly small): direct device-scope atomics (slow, correct).
__global__ __launch_bounds__(256) void mp_scatter_direct_kernel(
    const int* __restrict__ row, const int* __restrict__ col,
    const int* __restrict__ mask, const float* __restrict__ e,
    const float* __restrict__ p, float* __restrict__ out, int nnz)
{
    __shared__ float p_lds[NUM_RELATIONS];
    if (threadIdx.x < NUM_RELATIONS) p_lds[threadIdx.x] = p[threadIdx.x];
    __syncthreads();
    const int tid    = blockIdx.x * blockDim.x + threadIdx.x;
    const int stride = gridDim.x * blockDim.x;
    for (int i = tid; i < nnz; i += stride) {
        float v = p_lds[mask[i]] * e[row[i]];
        atomicAdd(&out[(unsigned)col[i] % NUM_ENTITIES], v);
    }
}

extern "C" void kernel_launch(void* const* d_in, const int* in_sizes, int n_in,
                              void* d_out, int out_size, void* d_ws, size_t ws_size,
                              hipStream_t stream) {
    const int*   indices = (const int*)d_in[0];
    const float* e       = (const float*)d_in[1];
    const float* p       = (const float*)d_in[2];
    const int*   mask    = (const int*)d_in[3];

    const int nnz = in_sizes[3];            // 8,000,000
    const int* row = indices;               // indices[0, :]
    const int* col = indices + nnz;         // indices[1, :]
    float* out = (float*)d_out;

    const size_t ws_needed = (size_t)RANGES * CHUNKS * RSIZE * sizeof(float); // 25.6 MB
    if (ws_size < ws_needed) {
        // Safety fallback (slow but correct).
        hipMemsetAsync(out, 0, (size_t)out_size * sizeof(float), stream);
        mp_scatter_direct_kernel<<<2048, 256, 0, stream>>>(row, col, mask, e, p, out, nnz);
        return;
    }

    float* ws = (float*)d_ws;

    mp_range_kernel<<<RANGES * CHUNKS, BLOCK, 0, stream>>>(row, col, mask, e, p, ws, nnz);

    const int nv4_total = (RSIZE / 4) * RANGES;  // 25000 float4s
    mp_reduce_kernel<<<(nv4_total + 255) / 256, 256, 0, stream>>>(ws, out);
}

// Round 7
// 72.238 us; speedup vs baseline: 5.8059x; 1.3527x over previous
//
#include <hip/hip_runtime.h>

// Problem constants (match reference setup_inputs()).
#define NUM_ENTITIES 100000
#define NUM_RELATIONS 256

// Range-partitioned LDS privatization.
#define RANGES 4
#define RSIZE (NUM_ENTITIES / RANGES)   // 25000 floats = 100000 B LDS
#define CHUNKS 64
#define BLOCK 1024

// Phase 1: each block owns (range r, edge-chunk c). Block mapping is
// range-major: range = blockIdx.x >> 6, chunk = blockIdx.x & 63. The 4
// range-siblings of a chunk are {c, c+64, c+128, c+192}; 64 % 8 == 0 so all
// siblings land on the SAME XCD under round-robin dispatch and share that
// XCD's L2 for the chunk's index data (cuts HBM re-fetch of the 4x logical
// read). 1024 threads/block = 16 waves/CU at 1 block/CU (LDS-capped).
__global__ __launch_bounds__(BLOCK) void mp_range_kernel(
    const int* __restrict__ row,     // [nnz]
    const int* __restrict__ col,     // [nnz]
    const int* __restrict__ mask,    // [nnz]
    const float* __restrict__ e,     // [E]
    const float* __restrict__ p,     // [R]
    float* __restrict__ ws,          // [RANGES * CHUNKS * RSIZE]
    int nnz)
{
    __shared__ float acc[RSIZE];
    __shared__ float p_lds[NUM_RELATIONS];

    if (threadIdx.x < NUM_RELATIONS) p_lds[threadIdx.x] = p[threadIdx.x];
    {   // zero LDS accumulator (vectorized)
        float4* a4 = reinterpret_cast<float4*>(acc);
        const float4 z = {0.f, 0.f, 0.f, 0.f};
        for (int i = threadIdx.x; i < RSIZE / 4; i += BLOCK) a4[i] = z;
    }
    __syncthreads();

    const int range = blockIdx.x >> 6;          // 0..RANGES-1
    const int chunk = blockIdx.x & (CHUNKS - 1);
    const int base  = range * RSIZE;

    const int nvec      = nnz >> 2;
    const int per_chunk = (nvec + CHUNKS - 1) / CHUNKS;
    const int v_lo      = chunk * per_chunk;
    const int v_hi      = min(v_lo + per_chunk, nvec);

    const int4* __restrict__ row4  = reinterpret_cast<const int4*>(row);
    const int4* __restrict__ col4  = reinterpret_cast<const int4*>(col);
    const int4* __restrict__ mask4 = reinterpret_cast<const int4*>(mask);

    for (int v = v_lo + (int)threadIdx.x; v < v_hi; v += BLOCK) {
        int4 c4 = col4[v];
        int4 r4 = row4[v];
        int4 m4 = mask4[v];

        int o0 = (int)((unsigned)c4.x % NUM_ENTITIES) - base;
        int o1 = (int)((unsigned)c4.y % NUM_ENTITIES) - base;
        int o2 = (int)((unsigned)c4.z % NUM_ENTITIES) - base;
        int o3 = (int)((unsigned)c4.w % NUM_ENTITIES) - base;

        if ((unsigned)o0 < RSIZE) atomicAdd(&acc[o0], p_lds[m4.x] * e[r4.x]);
        if ((unsigned)o1 < RSIZE) atomicAdd(&acc[o1], p_lds[m4.y] * e[r4.y]);
        if ((unsigned)o2 < RSIZE) atomicAdd(&acc[o2], p_lds[m4.z] * e[r4.z]);
        if ((unsigned)o3 < RSIZE) atomicAdd(&acc[o3], p_lds[m4.w] * e[r4.w]);
    }

    // Scalar tail (nnz not divisible by 4) — handled once per range.
    if (chunk == 0) {
        for (int i = (nvec << 2) + (int)threadIdx.x; i < nnz; i += BLOCK) {
            int o = (int)((unsigned)col[i] % NUM_ENTITIES) - base;
            if ((unsigned)o < RSIZE) atomicAdd(&acc[o], p_lds[mask[i]] * e[row[i]]);
        }
    }

    __syncthreads();

    // Flush full partial (writes everything -> ws needs no pre-zeroing).
    float4* __restrict__ dst =
        reinterpret_cast<float4*>(ws + ((size_t)range * CHUNKS + chunk) * RSIZE);
    const float4* a4 = reinterpret_cast<const float4*>(acc);
    for (int i = threadIdx.x; i < RSIZE / 4; i += BLOCK) dst[i] = a4[i];
}

// Phase 2: out[r*RSIZE + o] = sum over chunks c of ws[(r*CHUNKS + c)*RSIZE + o].
__global__ __launch_bounds__(256) void mp_reduce_kernel(
    const float* __restrict__ ws,
    float* __restrict__ out)
{
    const int nv4_per_range = RSIZE / 4;              // 6250
    const int nv4_total     = nv4_per_range * RANGES; // 25000
    int i = blockIdx.x * blockDim.x + threadIdx.x;
    if (i >= nv4_total) return;
    int r  = i / nv4_per_range;
    int ov = i - r * nv4_per_range;

    const float4* __restrict__ ws4 = reinterpret_cast<const float4*>(ws);
    size_t rbase = (size_t)r * CHUNKS * nv4_per_range;
    float4 s = ws4[rbase + ov];
    #pragma unroll 8
    for (int c = 1; c < CHUNKS; ++c) {
        float4 t = ws4[rbase + (size_t)c * nv4_per_range + ov];
        s.x += t.x; s.y += t.y; s.z += t.z; s.w += t.w;
    }
    reinterpret_cast<float4*>(out)[i] = s;
}

// Fallback (ws unexpectedly small): direct device-scope atomics (slow, correct).
__global__ __launch_bounds__(256) void mp_scatter_direct_kernel(
    const int* __restrict__ row, const int* __restrict__ col,
    const int* __restrict__ mask, const float* __restrict__ e,
    const float* __restrict__ p, float* __restrict__ out, int nnz)
{
    __shared__ float p_lds[NUM_RELATIONS];
    if (threadIdx.x < NUM_RELATIONS) p_lds[threadIdx.x] = p[threadIdx.x];
    __syncthreads();
    const int tid    = blockIdx.x * blockDim.x + threadIdx.x;
    const int stride = gridDim.x * blockDim.x;
    for (int i = tid; i < nnz; i += stride) {
        float v = p_lds[mask[i]] * e[row[i]];
        atomicAdd(&out[(unsigned)col[i] % NUM_ENTITIES], v);
    }
}

extern "C" void kernel_launch(void* const* d_in, const int* in_sizes, int n_in,
                              void* d_out, int out_size, void* d_ws, size_t ws_size,
                              hipStream_t stream) {
    const int*   indices = (const int*)d_in[0];
    const float* e       = (const float*)d_in[1];
    const float* p       = (const float*)d_in[2];
    const int*   mask    = (const int*)d_in[3];

    const int nnz = in_sizes[3];            // 8,000,000
    const int* row = indices;               // indices[0, :]
    const int* col = indices + nnz;         // indices[1, :]
    float* out = (float*)d_out;

    const size_t ws_needed = (size_t)RANGES * CHUNKS * RSIZE * sizeof(float); // 25.6 MB
    if (ws_size < ws_needed) {
        // Safety fallback (slow but correct).
        hipMemsetAsync(out, 0, (size_t)out_size * sizeof(float), stream);
        mp_scatter_direct_kernel<<<2048, 256, 0, stream>>>(row, col, mask, e, p, out, nnz);
        return;
    }

    float* ws = (float*)d_ws;

    mp_range_kernel<<<RANGES * CHUNKS, BLOCK, 0, stream>>>(row, col, mask, e, p, ws, nnz);

    const int nv4_total = (RSIZE / 4) * RANGES;  // 25000 float4s
    mp_reduce_kernel<<<(nv4_total + 255) / 256, 256, 0, stream>>>(ws, out);
}

// Round 8
// 68.360 us; speedup vs baseline: 6.1353x; 1.0567x over previous
//
#include <hip/hip_runtime.h>

// Problem constants (match reference setup_inputs()).
#define NUM_ENTITIES 100000
#define NUM_RELATIONS 256

// Range-partitioned LDS privatization.
#define RANGES 4
#define RSIZE (NUM_ENTITIES / RANGES)   // 25000 floats = 100000 B LDS
#define CHUNKS 64
#define BLOCK 1024

// Phase 1: each block owns (range r, edge-chunk c). Block mapping is
// range-major so the 4 range-siblings of a chunk ({c, c+64, c+128, c+192},
// 64 % 8 == 0) land on the SAME XCD and share its L2 for the chunk's index
// stream. 1024 threads = 16 waves/CU at 1 block/CU (LDS-capped).
// 2x-unrolled edge loop: both iterations' 6 int4 streaming loads are issued
// before either is consumed -> two independent load->gather->ds_add chains
// in flight per wave (latency-bound regime, occupancy can't rise).
__global__ __launch_bounds__(BLOCK) void mp_range_kernel(
    const int* __restrict__ row,     // [nnz]
    const int* __restrict__ col,     // [nnz]
    const int* __restrict__ mask,    // [nnz]
    const float* __restrict__ e,     // [E]
    const float* __restrict__ p,     // [R]
    float* __restrict__ ws,          // [RANGES * CHUNKS * RSIZE]
    int nnz)
{
    __shared__ float acc[RSIZE];
    __shared__ float p_lds[NUM_RELATIONS];

    if (threadIdx.x < NUM_RELATIONS) p_lds[threadIdx.x] = p[threadIdx.x];
    {   // zero LDS accumulator (vectorized)
        float4* a4 = reinterpret_cast<float4*>(acc);
        const float4 z = {0.f, 0.f, 0.f, 0.f};
        for (int i = threadIdx.x; i < RSIZE / 4; i += BLOCK) a4[i] = z;
    }
    __syncthreads();

    const int range = blockIdx.x >> 6;          // 0..RANGES-1
    const int chunk = blockIdx.x & (CHUNKS - 1);
    const int base  = range * RSIZE;

    const int nvec      = nnz >> 2;
    const int per_chunk = (nvec + CHUNKS - 1) / CHUNKS;
    const int v_lo      = chunk * per_chunk;
    const int v_hi      = min(v_lo + per_chunk, nvec);

    const int4* __restrict__ row4  = reinterpret_cast<const int4*>(row);
    const int4* __restrict__ col4  = reinterpret_cast<const int4*>(col);
    const int4* __restrict__ mask4 = reinterpret_cast<const int4*>(mask);

    for (int v = v_lo + (int)threadIdx.x; v < v_hi; v += 2 * BLOCK) {
        const int v2   = v + BLOCK;
        const bool b2  = v2 < v_hi;

        // Issue all streaming loads up front (two independent chains).
        int4 c4a = col4[v];
        int4 r4a = row4[v];
        int4 m4a = mask4[v];
        int4 c4b, r4b, m4b;
        if (b2) {
            c4b = col4[v2];
            r4b = row4[v2];
            m4b = mask4[v2];
        }

        // Chain A
        {
            int o0 = (int)((unsigned)c4a.x % NUM_ENTITIES) - base;
            int o1 = (int)((unsigned)c4a.y % NUM_ENTITIES) - base;
            int o2 = (int)((unsigned)c4a.z % NUM_ENTITIES) - base;
            int o3 = (int)((unsigned)c4a.w % NUM_ENTITIES) - base;
            if ((unsigned)o0 < RSIZE) atomicAdd(&acc[o0], p_lds[m4a.x] * e[r4a.x]);
            if ((unsigned)o1 < RSIZE) atomicAdd(&acc[o1], p_lds[m4a.y] * e[r4a.y]);
            if ((unsigned)o2 < RSIZE) atomicAdd(&acc[o2], p_lds[m4a.z] * e[r4a.z]);
            if ((unsigned)o3 < RSIZE) atomicAdd(&acc[o3], p_lds[m4a.w] * e[r4a.w]);
        }
        // Chain B
        if (b2) {
            int o0 = (int)((unsigned)c4b.x % NUM_ENTITIES) - base;
            int o1 = (int)((unsigned)c4b.y % NUM_ENTITIES) - base;
            int o2 = (int)((unsigned)c4b.z % NUM_ENTITIES) - base;
            int o3 = (int)((unsigned)c4b.w % NUM_ENTITIES) - base;
            if ((unsigned)o0 < RSIZE) atomicAdd(&acc[o0], p_lds[m4b.x] * e[r4b.x]);
            if ((unsigned)o1 < RSIZE) atomicAdd(&acc[o1], p_lds[m4b.y] * e[r4b.y]);
            if ((unsigned)o2 < RSIZE) atomicAdd(&acc[o2], p_lds[m4b.z] * e[r4b.z]);
            if ((unsigned)o3 < RSIZE) atomicAdd(&acc[o3], p_lds[m4b.w] * e[r4b.w]);
        }
    }

    // Scalar tail (nnz not divisible by 4) — handled once per range.
    if (chunk == 0) {
        for (int i = (nvec << 2) + (int)threadIdx.x; i < nnz; i += BLOCK) {
            int o = (int)((unsigned)col[i] % NUM_ENTITIES) - base;
            if ((unsigned)o < RSIZE) atomicAdd(&acc[o], p_lds[mask[i]] * e[row[i]]);
        }
    }

    __syncthreads();

    // Flush full partial (writes everything -> ws needs no pre-zeroing).
    float4* __restrict__ dst =
        reinterpret_cast<float4*>(ws + ((size_t)range * CHUNKS + chunk) * RSIZE);
    const float4* a4 = reinterpret_cast<const float4*>(acc);
    for (int i = threadIdx.x; i < RSIZE / 4; i += BLOCK) dst[i] = a4[i];
}

// Phase 2: out[r*RSIZE + o] = sum over chunks c of ws[(r*CHUNKS + c)*RSIZE + o].
__global__ __launch_bounds__(256) void mp_reduce_kernel(
    const float* __restrict__ ws,
    float* __restrict__ out)
{
    const int nv4_per_range = RSIZE / 4;              // 6250
    const int nv4_total     = nv4_per_range * RANGES; // 25000
    int i = blockIdx.x * blockDim.x + threadIdx.x;
    if (i >= nv4_total) return;
    int r  = i / nv4_per_range;
    int ov = i - r * nv4_per_range;

    const float4* __restrict__ ws4 = reinterpret_cast<const float4*>(ws);
    size_t rbase = (size_t)r * CHUNKS * nv4_per_range;
    float4 s = ws4[rbase + ov];
    #pragma unroll 8
    for (int c = 1; c < CHUNKS; ++c) {
        float4 t = ws4[rbase + (size_t)c * nv4_per_range + ov];
        s.x += t.x; s.y += t.y; s.z += t.z; s.w += t.w;
    }
    reinterpret_cast<float4*>(out)[i] = s;
}

// Fallback (ws unexpectedly small): direct device-scope atomics (slow, correct).
__global__ __launch_bounds__(256) void mp_scatter_direct_kernel(
    const int* __restrict__ row, const int* __restrict__ col,
    const int* __restrict__ mask, const float* __restrict__ e,
    const float* __restrict__ p, float* __restrict__ out, int nnz)
{
    __shared__ float p_lds[NUM_RELATIONS];
    if (threadIdx.x < NUM_RELATIONS) p_lds[threadIdx.x] = p[threadIdx.x];
    __syncthreads();
    const int tid    = blockIdx.x * blockDim.x + threadIdx.x;
    const int stride = gridDim.x * blockDim.x;
    for (int i = tid; i < nnz; i += stride) {
        float v = p_lds[mask[i]] * e[row[i]];
        atomicAdd(&out[(unsigned)col[i] % NUM_ENTITIES], v);
    }
}

extern "C" void kernel_launch(void* const* d_in, const int* in_sizes, int n_in,
                              void* d_out, int out_size, void* d_ws, size_t ws_size,
                              hipStream_t stream) {
    const int*   indices = (const int*)d_in[0];
    const float* e       = (const float*)d_in[1];
    const float* p       = (const float*)d_in[2];
    const int*   mask    = (const int*)d_in[3];

    const int nnz = in_sizes[3];            // 8,000,000
    const int* row = indices;               // indices[0, :]
    const int* col = indices + nnz;         // indices[1, :]
    float* out = (float*)d_out;

    const size_t ws_needed = (size_t)RANGES * CHUNKS * RSIZE * sizeof(float); // 25.6 MB
    if (ws_size < ws_needed) {
        // Safety fallback (slow but correct).
        hipMemsetAsync(out, 0, (size_t)out_size * sizeof(float), stream);
        mp_scatter_direct_kernel<<<2048, 256, 0, stream>>>(row, col, mask, e, p, out, nnz);
        return;
    }

    float* ws = (float*)d_ws;

    mp_range_kernel<<<RANGES * CHUNKS, BLOCK, 0, stream>>>(row, col, mask, e, p, ws, nnz);

    const int nv4_total = (RSIZE / 4) * RANGES;  // 25000 float4s
    mp_reduce_kernel<<<(nv4_total + 255) / 256, 256, 0, stream>>>(ws, out);
}